// Round 10
// baseline (1199.126 us; speedup 1.0000x reference)
//
#include <hip/hip_runtime.h>

// Problem sizes
// B=8 M=4 T=2048 E=768 P=256 K=64 V=64 H=128 NEXP=16 COMB=384 HID=192
// tokens NT = 65536, sequences NSEQ = 32
// Round 10: full producer/consumer fusion. Two dispatches: k_prep, k_fused.
// k_fused (256 blocks, all co-resident):
//   blocks 0-31 : GRU. ulds loaded per-quad (128 rows = 1 gemm1 tile),
//                 gated on gflag[seq] bit qd; quad-entry xq recompute.
//                 Publishes prog[seq] every 4 chunks (R9 mechanism).
//   blocks 32+  : phase A = gemm1+attention tiles (tg-major claim order,
//                 release-atomicOr gflag bit per tile), then
//                 phase B = MLP tiles gated on prog[seq] (R9 body).

typedef unsigned short u16;
typedef float f32x4 __attribute__((ext_vector_type(4)));
typedef short s16x8 __attribute__((ext_vector_type(8)));
typedef unsigned u32x2 __attribute__((ext_vector_type(2)));
typedef unsigned u32x4 __attribute__((ext_vector_type(4)));

#define DI static __device__ __forceinline__

#define L2E  1.44269504088896340736f
#define L2E2 2.88539008177792681472f

DI u16 f2b(float f) {  // fp32 -> bf16 RNE
  unsigned u = __builtin_bit_cast(unsigned, f);
  u += 0x7fffu + ((u >> 16) & 1u);
  return (u16)(u >> 16);
}
DI unsigned pk2(float lo, float hi) {  // 2x fp32 -> packed 2x bf16 (RNE), 1 inst
  unsigned r;
  asm("v_cvt_pk_bf16_f32 %0, %1, %2" : "=v"(r) : "v"(lo), "v"(hi));
  return r;
}
DI u16 f2b_cvt(float f) {
  return (u16)pk2(f, f);
}
DI float b2f(u16 s) { return __builtin_bit_cast(float, ((unsigned)s) << 16); }
DI float rcp_fast(float x) { return __builtin_amdgcn_rcpf(x); }
DI float exp2_fast(float x) { return __builtin_exp2f(x); }  // v_exp_f32
DI f32x4 mfma16(s16x8 a, s16x8 b, f32x4 c) {
  return __builtin_amdgcn_mfma_f32_16x16x32_bf16(a, b, c, 0, 0, 0);
}

// ---- workspace layout (bytes) ----
#define OFF_COMB   0ull            // u16 [65536][384]  (proc | rus)      50331648
#define OFF_URS    50331648ull     // f32 [32][2048][4] {U, rbar, sbar, 0} 1048576
#define OFF_TPWB   51380736ull     // u16 [256][768]                        393216
#define OFF_WHHB   51773952ull     // u16 [384][128]  (exp2-prescaled)       98304
#define OFF_W1B    51872256ull     // u16 [192][384]                        147456
#define OFF_W2B    52019712ull     // u16 [16][192]                           6144
#define OFF_WABC   52025856ull     // f32 wA[256] wB[256] wC[256]             3072
#define OFF_CABC   52028928ull     // f32 cA cB cC pad                          16
#define OFF_GX     52028944ull     // f32 gxu[384] gxr[384] gxs[384] gxc[384] 6144
#define OFF_PROG   52035088ull     // i32 prog[32] GRU chunk progress          128
#define OFF_GFLAG  52035216ull     // i32 gflag[32] gemm1 tile bitmask         128
// gx rows j<256 (r,z): scaled by -log2e (includes folded b_hh).
// gx rows j>=256 (n): scaled by +2*log2e. whhb rows likewise prescaled.

// =====================================================================
// K0: derived weights + bf16 conversions (with exp2 prescale)
// =====================================================================
__global__ __launch_bounds__(512) void k_prep(
    const float* __restrict__ qw, const float* __restrict__ qb,
    const float* __restrict__ kw, const float* __restrict__ kb,
    const float* __restrict__ vw, const float* __restrict__ vb,
    const float* __restrict__ wih, const float* __restrict__ bih,
    const float* __restrict__ bhh,
    const float* __restrict__ tpw, const float* __restrict__ whh,
    const float* __restrict__ w1, const float* __restrict__ w2,
    u16* __restrict__ tpwb, u16* __restrict__ whhb,
    u16* __restrict__ w1b, u16* __restrict__ w2b,
    float* __restrict__ wabc, float* __restrict__ cabc, float* __restrict__ gx,
    int* __restrict__ prog, int* __restrict__ gflag) {
  const int tid = threadIdx.x, bid = blockIdx.x;
  if (bid == 0 && tid < 256) {
    int p = tid;
    float a = 0.f, b = 0.f, c = 0.f;
    for (int j = 0; j < 64; j++) {
      float q = qw[j * 256 + p];
      a += q * kw[2 * j]; b += q * kw[2 * j + 1]; c += q * kb[j];
    }
    wabc[p] = a; wabc[256 + p] = b; wabc[512 + p] = c;
    if (p == 0) {
      float ca = 0.f, cb = 0.f, cc = 0.f;
      for (int j = 0; j < 64; j++) {
        ca += qb[j] * kw[2 * j]; cb += qb[j] * kw[2 * j + 1]; cc += qb[j] * kb[j];
      }
      cabc[0] = ca; cabc[1] = cb; cabc[2] = cc; cabc[3] = 0.f;
    }
  }
  if (bid == 1 && tid < 384) {
    int j = tid;
    float r = 0.f, s = 0.f, c0 = 0.f;
    for (int v = 0; v < 64; v++) {
      float w = wih[j * 65 + 1 + v];
      r += w * vw[2 * v]; s += w * vw[2 * v + 1]; c0 += w * vb[v];
    }
    float xc = c0 + bih[j] + (j < 256 ? bhh[j] : 0.f);
    float sc = (j < 256) ? -L2E : L2E2;
    gx[j] = wih[j * 65] * sc; gx[384 + j] = r * sc;
    gx[768 + j] = s * sc;     gx[1152 + j] = xc * sc;
  }
  if (bid == 2 && tid < 32) { prog[tid] = 0; gflag[tid] = 0; }
  const int n1 = 768 * 256, n2 = 384 * 128, n3 = 192 * 384, n4 = 16 * 192;
  const int total = n1 + n2 + n3 + n4;
  for (int i = bid * blockDim.x + tid; i < total; i += gridDim.x * blockDim.x) {
    if (i < n1) tpwb[i] = f2b(tpw[i]);
    else if (i < n1 + n2) {
      int loc = i - n1;
      float sc = (loc < 256 * 128) ? L2E : L2E2;
      whhb[loc] = f2b(whh[loc] * sc);
    }
    else if (i < n1 + n2 + n3) w1b[i - n1 - n2] = f2b(w1[i - n1 - n2]);
    else w2b[i - n1 - n2 - n3] = f2b(w2[i - n1 - n2 - n3]);
  }
}

// =====================================================================
// K1: the fused mega-kernel. 256 blocks x 512 threads.
// =====================================================================
#define PSTR 264
__global__ __launch_bounds__(512, 1) void k_fused(
    const float* __restrict__ te, const float* __restrict__ tpb,
    const u16* __restrict__ tpwb, u16* __restrict__ comb,
    const float* __restrict__ U, const float* __restrict__ R,
    const float* __restrict__ S, const float* __restrict__ wabc,
    const float* __restrict__ cabc, float* __restrict__ urs,
    const u16* __restrict__ whhb, const float* __restrict__ bhh,
    const float* __restrict__ gx, const u16* __restrict__ w1b,
    const float* __restrict__ b1, const u16* __restrict__ w2b,
    const float* __restrict__ b2, float* __restrict__ out,
    int* __restrict__ prog, int* __restrict__ gflag) {
  __shared__ __align__(16) union {
    struct {
      u16 hbuf[2][128];          //   512 B
      u16 hist[2][32][128];      // 16384 B
      float ulds[2049][4];       // 32784 B
    } g;
    u16 gm[128 * PSTR];          // 67584 B gemm1 staging/ptile
    u16 m[24576];                // 49152 B mlp
  } SM;
  const int tid = threadIdx.x;
  const int bid = blockIdx.x;
  const int lane = tid & 63, w = tid >> 6;
  const int c = lane & 15, g4 = lane >> 4;

  if (bid < 32) {
    // ================= GRU path =================
    auto& hbuf = SM.g.hbuf;
    auto& hist = SM.g.hist;
    auto& ulds = SM.g.ulds;
    const int seq = bid;

    const int j = w * 16 + c;                  // this lane's H column (0..127)
    s16x8 bfr[3][4];
    #pragma unroll
    for (int g = 0; g < 3; g++) {
      int n = g * 128 + j;
      #pragma unroll
      for (int kt = 0; kt < 4; kt++)
        bfr[g][kt] = *(const s16x8*)(whhb + n * 128 + kt * 32 + g4 * 8);
    }
    float gxv[3][4];
    #pragma unroll
    for (int g = 0; g < 3; g++) {
      int jj = g * 128 + j;
      gxv[g][0] = gx[jj];        gxv[g][1] = gx[384 + jj];
      gxv[g][2] = gx[768 + jj];  gxv[g][3] = gx[1152 + jj];
    }
    const float bhn = bhh[256 + j] * L2E2;
    const f32x4 nseed = (f32x4)(bhn);

    if (tid < 128) { hbuf[0][tid] = 0; hbuf[1][tid] = 0; }
    float hprev = 0.f;
    __syncthreads();  // hbuf visible

    u16* rbase = comb + (long)seq * 2048 * 384 + 256;
    float xq0 = 0.f, xq1 = 0.f, xq2 = 0.f;
    for (int qd = 0; qd < 16; qd++) {
      // gate on gemm1 tile qd of this sequence (produces urs rows qd*128..+127)
      if (tid == 0) {
        while (!((__hip_atomic_load(&gflag[seq], __ATOMIC_RELAXED,
                                    __HIP_MEMORY_SCOPE_AGENT) >> qd) & 1))
          __builtin_amdgcn_s_sleep(8);
      }
      __syncthreads();
      (void)__hip_atomic_load(&gflag[seq], __ATOMIC_ACQUIRE,
                              __HIP_MEMORY_SCOPE_AGENT);  // cache inv for urs
      if (tid < 128)
        *(f32x4*)&ulds[qd * 128 + tid][0] =
            *(const f32x4*)(urs + ((long)seq * 2048 + qd * 128 + tid) * 4);
      __syncthreads();  // segment visible (drains vmcnt+lgkm of loaders)
      {  // quad-entry xq recompute (cross-quad prefetched value was stale)
        f32x4 u0 = *(const f32x4*)&ulds[qd * 128][0];
        xq0 = gxv[0][3] + u0[0] * gxv[0][0] + u0[1] * gxv[0][1] + u0[2] * gxv[0][2];
        xq1 = gxv[1][3] + u0[0] * gxv[1][0] + u0[1] * gxv[1][1] + u0[2] * gxv[1][2];
        xq2 = gxv[2][3] + u0[0] * gxv[2][0] + u0[1] * gxv[2][1] + u0[2] * gxv[2][2];
      }
      for (int cc = 0; cc < 4; cc++) {
        const int chunk = qd * 4 + cc;
        const float* up = &ulds[chunk * 32][0];
        u16* hw = &hist[chunk & 1][0][j];
        #pragma unroll 8
        for (int s = 0; s < 32; s++) {
          s16x8 af[4];
          #pragma unroll
          for (int kt = 0; kt < 4; kt++)
            af[kt] = *(const s16x8*)&hbuf[s & 1][kt * 32 + g4 * 8];
          f32x4 aA[3], aB[3];
          #pragma unroll
          for (int g = 0; g < 3; g++) {
            f32x4 x0 = (f32x4)(0.f);
            f32x4 x1 = (g == 2) ? nseed : (f32x4)(0.f);
            x0 = mfma16(af[0], bfr[g][0], x0);
            x1 = mfma16(af[2], bfr[g][2], x1);
            x0 = mfma16(af[1], bfr[g][1], x0);
            x1 = mfma16(af[3], bfr[g][3], x1);
            aA[g] = x0; aB[g] = x1;
          }
          f32x4 un = *(const f32x4*)(up + (s + 1) * 4);
          float nx0 = gxv[0][3] + un[0] * gxv[0][0] + un[1] * gxv[0][1] + un[2] * gxv[0][2];
          float nx1 = gxv[1][3] + un[0] * gxv[1][0] + un[1] * gxv[1][1] + un[2] * gxv[1][2];
          float nx2 = gxv[2][3] + un[0] * gxv[2][0] + un[1] * gxv[2][1] + un[2] * gxv[2][2];
          float hr2 = aA[0][0] + aB[0][0];
          float hz2 = aA[1][0] + aB[1][0];
          float hn2 = aA[2][0] + aB[2][0];
          float r = rcp_fast(1.f + exp2_fast(xq0 - hr2));
          float z = rcp_fast(1.f + exp2_fast(xq1 - hz2));
          float e = exp2_fast(xq2 + r * hn2);
          float n = __builtin_fmaf(-2.f, rcp_fast(e + 1.f), 1.f);
          float h = z * (hprev - n) + n;
          hprev = h;
          u16 hb = f2b_cvt(h);
          hbuf[(s + 1) & 1][j] = hb;
          hw[s * 128] = hb;
          __syncthreads();
          xq0 = nx0; xq1 = nx1; xq2 = nx2;
        }
        // flush chunk history: 32 rows x 256 B, coalesced fire-and-forget
        const int t0 = chunk * 32;
        {
          int row = tid >> 4, part = tid & 15;
          s16x8 v = *(const s16x8*)&hist[chunk & 1][row][part * 8];
          *(s16x8*)(rbase + (long)(t0 + row) * 384 + part * 8) = v;
        }
        // publish GRU progress every 4 chunks (drain, then release store)
        if ((chunk & 3) == 3) {
          __syncthreads();
          if (tid == 0)
            __hip_atomic_store(&prog[seq], chunk + 1,
                               __ATOMIC_RELEASE, __HIP_MEMORY_SCOPE_AGENT);
        }
      }
    }
  } else {
    // ================= worker path =================
    const int wm = w >> 2, wn = w & 3;

    // ---- phase A: gemm1 + fused attention tiles (tg-major claim) ----
    for (int q = bid - 32; q < 512; q += 224) {
      const int tg = q >> 5, sq = q & 31;   // tile tg of sequence sq
      const long row0 = ((long)sq * 16 + tg) * 128;  // global token row
      u16* Als = SM.gm;                  // 128x64
      u16* Bls = SM.gm + 8192;           // 256x64
      u16* ptile = SM.gm;                // 128xPSTR (reuse after MFMA loop)

      f32x4 acc[4][4];
      #pragma unroll
      for (int i = 0; i < 4; i++)
        #pragma unroll
        for (int jj = 0; jj < 4; jj++) acc[i][jj] = (f32x4)(0.f);

      for (int kk = 0; kk < 12; kk++) {
        #pragma unroll
        for (int ii = 0; ii < 2; ii++) {
          int idx = tid + 512 * ii;
          int row = idx >> 3, kb = idx & 7;
          const float* g = te + (row0 + row) * 768 + kk * 64 + kb * 8;
          f32x4 p0 = *(const f32x4*)g;
          f32x4 p1 = *(const f32x4*)(g + 4);
          u32x4 v;
          v[0] = pk2(p0[0], p0[1]); v[1] = pk2(p0[2], p0[3]);
          v[2] = pk2(p1[0], p1[1]); v[3] = pk2(p1[2], p1[3]);
          *(u32x4*)&Als[row * 64 + ((kb ^ (row & 7)) << 3)] = v;
        }
        #pragma unroll
        for (int ii = 0; ii < 4; ii++) {
          int idx = tid + 512 * ii;
          int n = idx >> 3, kb = idx & 7;
          s16x8 v = *(const s16x8*)(tpwb + n * 768 + kk * 64 + kb * 8);
          *(s16x8*)&Bls[n * 64 + ((kb ^ (n & 7)) << 3)] = v;
        }
        __syncthreads();
        #pragma unroll
        for (int kt = 0; kt < 2; kt++) {
          s16x8 af[4], bf[4];
          #pragma unroll
          for (int mt = 0; mt < 4; mt++) {
            int row = wm * 64 + mt * 16 + c;
            af[mt] = *(const s16x8*)&Als[row * 64 + (((kt * 4 + g4) ^ (row & 7)) << 3)];
          }
          #pragma unroll
          for (int nt = 0; nt < 4; nt++) {
            int n = wn * 64 + nt * 16 + c;
            bf[nt] = *(const s16x8*)&Bls[n * 64 + (((kt * 4 + g4) ^ (n & 7)) << 3)];
          }
          #pragma unroll
          for (int mt = 0; mt < 4; mt++)
            #pragma unroll
            for (int nt = 0; nt < 4; nt++)
              acc[mt][nt] = mfma16(af[mt], bf[nt], acc[mt][nt]);
        }
        __syncthreads();
      }
      // epilogue: relu + bias -> comb (global) and ptile (LDS)
      #pragma unroll
      for (int nt = 0; nt < 4; nt++) {
        int col = wn * 64 + nt * 16 + c;
        float bias = tpb[col];
        #pragma unroll
        for (int mt = 0; mt < 4; mt++)
          #pragma unroll
          for (int r = 0; r < 4; r++) {
            int lr = wm * 64 + mt * 16 + g4 * 4 + r;
            float v = fmaxf(acc[mt][nt][r] + bias, 0.f);
            u16 hv = f2b(v);
            comb[(row0 + lr) * 384 + col] = hv;
            ptile[lr * PSTR + col] = hv;
          }
      }
      __syncthreads();
      // fused attention: wave w handles tokens row0 + w*16 .. +15
      {
        const int tok16 = lane >> 2;
        const int part = lane & 3;
        const int lr = w * 16 + tok16;
        const long tokg = row0 + lr;
        const int t = (int)(tokg & 2047);
        const int seq = (int)(tokg >> 11);
        const int m = seq & 3;

        float a = 0.f, b = 0.f, cd = 0.f;
        const u16* prow = &ptile[lr * PSTR + part * 64];
        #pragma unroll
        for (int i = 0; i < 8; i++) {
          s16x8 pv = *(const s16x8*)(prow + i * 8);
          int col0 = part * 64 + i * 8;
          f32x4 wa0 = *(const f32x4*)(wabc + col0);
          f32x4 wa1 = *(const f32x4*)(wabc + col0 + 4);
          f32x4 wb0 = *(const f32x4*)(wabc + 256 + col0);
          f32x4 wb1 = *(const f32x4*)(wabc + 256 + col0 + 4);
          f32x4 wc0 = *(const f32x4*)(wabc + 512 + col0);
          f32x4 wc1 = *(const f32x4*)(wabc + 512 + col0 + 4);
          #pragma unroll
          for (int k = 0; k < 4; k++) {
            float p = b2f((u16)pv[k]);
            a += p * wa0[k]; b += p * wb0[k]; cd += p * wc0[k];
          }
          #pragma unroll
          for (int k = 0; k < 4; k++) {
            float p = b2f((u16)pv[4 + k]);
            a += p * wa1[k]; b += p * wb1[k]; cd += p * wc1[k];
          }
        }
        #pragma unroll
        for (int off = 1; off <= 2; off <<= 1) {
          a += __shfl_xor(a, off); b += __shfl_xor(b, off); cd += __shfl_xor(cd, off);
        }
        a += cabc[0]; b += cabc[1]; cd += cabc[2];

        float rv[3], sv[3], sc[3];
        #pragma unroll
        for (int n = 0; n < 3; n++) {
          int o = n + (n >= m ? 1 : 0);
          long idx = ((long)seq * 4 + o) * 2048 + t;
          rv[n] = R[idx]; sv[n] = S[idx];
          sc[n] = (a * rv[n] + b * sv[n] + cd) * 0.125f;
        }
        float mx = fmaxf(sc[0], fmaxf(sc[1], sc[2]));
        float e0 = __expf(sc[0] - mx), e1 = __expf(sc[1] - mx), e2 = __expf(sc[2] - mx);
        float inv = rcp_fast(e0 + e1 + e2);
        float rb = (e0 * rv[0] + e1 * rv[1] + e2 * rv[2]) * inv;
        float sb = (e0 * sv[0] + e1 * sv[1] + e2 * sv[2]) * inv;
        if (part == 0) {
          f32x4 v; v[0] = U[tokg]; v[1] = rb; v[2] = sb; v[3] = 0.f;
          *(f32x4*)(urs + ((long)seq * 2048 + t) * 4) = v;
        }
      }
      // publish tile: drain all threads' comb/urs stores, release-or the bit
      __syncthreads();
      if (tid == 0)
        __hip_atomic_fetch_or(&gflag[sq], 1 << tg,
                              __ATOMIC_RELEASE, __HIP_MEMORY_SCOPE_AGENT);
    }

    // ---- phase B: MLP tiles gated on GRU progress (R9 body) ----
    u16* Als = SM.m;             // 128x64
    u16* Bls = SM.m + 8192;      // 192x64
    u16* Hls = SM.m;             // 128x192 (reuse after barrier)

    s16x8 w2f[6];
    #pragma unroll
    for (int kt = 0; kt < 6; kt++)
      w2f[kt] = *(const s16x8*)(w2b + c * 192 + kt * 32 + g4 * 8);
    const float b2v = b2[c];

    for (int q = bid - 32; q < 512; q += 224) {
      const int tg = q >> 5, seq = q & 31;
      const long row0 = (long)seq * 2048 + (long)tg * 128;
      const int need = (tg + 1) * 4;
      if (tid == 0) {
        while (__hip_atomic_load(&prog[seq], __ATOMIC_RELAXED,
                                 __HIP_MEMORY_SCOPE_AGENT) < need)
          __builtin_amdgcn_s_sleep(8);
      }
      __syncthreads();   // readiness seen by all; orders prior LDS reuse
      (void)__hip_atomic_load(&prog[seq], __ATOMIC_ACQUIRE,
                              __HIP_MEMORY_SCOPE_AGENT);  // inv for comb reads

      f32x4 acc[4][3];
      #pragma unroll
      for (int i = 0; i < 4; i++)
        #pragma unroll
        for (int jj = 0; jj < 3; jj++) acc[i][jj] = (f32x4)(0.f);

      for (int kc = 0; kc < 6; kc++) {
        #pragma unroll
        for (int ii = 0; ii < 2; ii++) {
          int idx = tid + 512 * ii;
          int row = idx >> 3, kb = idx & 7;
          s16x8 v = *(const s16x8*)(comb + (row0 + row) * 384 + kc * 64 + kb * 8);
          *(s16x8*)&Als[row * 64 + ((kb ^ (row & 7)) << 3)] = v;
        }
        #pragma unroll
        for (int ii = 0; ii < 3; ii++) {
          int idx = tid + 512 * ii;
          if (idx < 1536) {
            int n = idx >> 3, kb = idx & 7;
            s16x8 v = *(const s16x8*)(w1b + n * 384 + kc * 64 + kb * 8);
            *(s16x8*)&Bls[n * 64 + ((kb ^ (n & 7)) << 3)] = v;
          }
        }
        __syncthreads();
        #pragma unroll
        for (int kt = 0; kt < 2; kt++) {
          s16x8 af[4], bf[3];
          #pragma unroll
          for (int mt = 0; mt < 4; mt++) {
            int row = wm * 64 + mt * 16 + c;
            af[mt] = *(const s16x8*)&Als[row * 64 + (((kt * 4 + g4) ^ (row & 7)) << 3)];
          }
          #pragma unroll
          for (int nt = 0; nt < 3; nt++) {
            int n = wn * 48 + nt * 16 + c;
            bf[nt] = *(const s16x8*)&Bls[n * 64 + (((kt * 4 + g4) ^ (n & 7)) << 3)];
          }
          #pragma unroll
          for (int mt = 0; mt < 4; mt++)
            #pragma unroll
            for (int nt = 0; nt < 3; nt++)
              acc[mt][nt] = mfma16(af[mt], bf[nt], acc[mt][nt]);
        }
        __syncthreads();
      }
      // hid -> LDS (bf16, swizzled)
      #pragma unroll
      for (int nt = 0; nt < 3; nt++) {
        int col = wn * 48 + nt * 16 + c;
        float bias = b1[col];
        int cb = col >> 3, cl = col & 7;
        #pragma unroll
        for (int mt = 0; mt < 4; mt++)
          #pragma unroll
          for (int r = 0; r < 4; r++) {
            int row = wm * 64 + mt * 16 + g4 * 4 + r;
            float v = fmaxf(acc[mt][nt][r] + bias, 0.f);
            Hls[row * 192 + ((cb ^ (row & 7)) << 3) + cl] = f2b(v);
          }
      }
      __syncthreads();
      // gemm2: 16 outputs, K=192
      f32x4 a2 = (f32x4)(0.f);
      const int row = w * 16 + c, r7 = row & 7;
      #pragma unroll
      for (int kt = 0; kt < 6; kt++) {
        s16x8 af = *(const s16x8*)&Hls[row * 192 + (((kt * 4 + g4) ^ r7) << 3)];
        a2 = mfma16(af, w2f[kt], a2);
      }
      #pragma unroll
      for (int r = 0; r < 4; r++) {
        long grow = row0 + w * 16 + g4 * 4 + r;
        out[grow * 16 + c] = a2[r] + b2v;
      }
      __syncthreads();   // Hls reads done before next tile's Als staging
    }
  }
}

// =====================================================================
extern "C" void kernel_launch(void* const* d_in, const int* in_sizes, int n_in,
                              void* d_out, int out_size, void* d_ws, size_t ws_size,
                              hipStream_t stream) {
  (void)in_sizes; (void)n_in; (void)out_size; (void)ws_size;
  const float* te  = (const float*)d_in[0];
  const float* U   = (const float*)d_in[1];
  const float* R   = (const float*)d_in[2];
  const float* S   = (const float*)d_in[3];
  const float* tpw = (const float*)d_in[4];
  const float* tpb = (const float*)d_in[5];
  const float* qw  = (const float*)d_in[6];
  const float* qb  = (const float*)d_in[7];
  const float* kw  = (const float*)d_in[8];
  const float* kb  = (const float*)d_in[9];
  const float* vw  = (const float*)d_in[10];
  const float* vb  = (const float*)d_in[11];
  const float* wih = (const float*)d_in[12];
  const float* whh = (const float*)d_in[13];
  const float* bih = (const float*)d_in[14];
  const float* bhh = (const float*)d_in[15];
  const float* w1  = (const float*)d_in[16];
  const float* b1  = (const float*)d_in[17];
  const float* w2  = (const float*)d_in[18];
  const float* b2  = (const float*)d_in[19];

  char* ws = (char*)d_ws;
  u16*   comb = (u16*)(ws + OFF_COMB);
  float* urs  = (float*)(ws + OFF_URS);
  u16*   tpwb = (u16*)(ws + OFF_TPWB);
  u16*   whhb = (u16*)(ws + OFF_WHHB);
  u16*   w1b  = (u16*)(ws + OFF_W1B);
  u16*   w2b  = (u16*)(ws + OFF_W2B);
  float* wabc = (float*)(ws + OFF_WABC);
  float* cabc = (float*)(ws + OFF_CABC);
  float* gx   = (float*)(ws + OFF_GX);
  int*   prog = (int*)(ws + OFF_PROG);
  int*   gflag= (int*)(ws + OFF_GFLAG);
  float* out  = (float*)d_out;

  hipLaunchKernelGGL(k_prep, dim3(32), dim3(512), 0, stream,
                     qw, qb, kw, kb, vw, vb, wih, bih, bhh, tpw, whh, w1, w2,
                     tpwb, whhb, w1b, w2b, wabc, cabc, gx, prog, gflag);
  hipLaunchKernelGGL(k_fused, dim3(256), dim3(512), 0, stream,
                     te, tpb, tpwb, comb, U, R, S, wabc, cabc, urs,
                     whhb, bhh, gx, w1b, b1, w2b, b2, out, prog, gflag);
}

// Round 11
// 1174.587 us; speedup vs baseline: 1.0209x; 1.0209x over previous
//
#include <hip/hip_runtime.h>

// Problem sizes
// B=8 M=4 T=2048 E=768 P=256 K=64 V=64 H=128 NEXP=16 COMB=384 HID=192
// tokens NT = 65536, sequences NSEQ = 32
// Round 11: REVERT to R9 (session best, 1180.7 µs). R10's gemm1 fusion put
// gate/load waits on the GRU's serial critical path (-18 µs net). R9's
// asymmetric overlap (GRU never waits; MLP workers gate on GRU progress)
// is the proven optimum. k_gru floor ~800 µs bracketed by 5 rounds of
// nulls; remaining levers have negative measured EV. This is the final
// configuration.

typedef unsigned short u16;
typedef float f32x4 __attribute__((ext_vector_type(4)));
typedef short s16x8 __attribute__((ext_vector_type(8)));
typedef unsigned u32x2 __attribute__((ext_vector_type(2)));
typedef unsigned u32x4 __attribute__((ext_vector_type(4)));

#define DI static __device__ __forceinline__

#define L2E  1.44269504088896340736f
#define L2E2 2.88539008177792681472f

DI u16 f2b(float f) {  // fp32 -> bf16 RNE
  unsigned u = __builtin_bit_cast(unsigned, f);
  u += 0x7fffu + ((u >> 16) & 1u);
  return (u16)(u >> 16);
}
DI unsigned pk2(float lo, float hi) {  // 2x fp32 -> packed 2x bf16 (RNE), 1 inst
  unsigned r;
  asm("v_cvt_pk_bf16_f32 %0, %1, %2" : "=v"(r) : "v"(lo), "v"(hi));
  return r;
}
DI u16 f2b_cvt(float f) {
  return (u16)pk2(f, f);
}
DI float b2f(u16 s) { return __builtin_bit_cast(float, ((unsigned)s) << 16); }
DI float rcp_fast(float x) { return __builtin_amdgcn_rcpf(x); }
DI float exp2_fast(float x) { return __builtin_exp2f(x); }  // v_exp_f32
DI f32x4 mfma16(s16x8 a, s16x8 b, f32x4 c) {
  return __builtin_amdgcn_mfma_f32_16x16x32_bf16(a, b, c, 0, 0, 0);
}

// ---- workspace layout (bytes) ----
#define OFF_COMB   0ull            // u16 [65536][384]  (proc | rus)      50331648
#define OFF_URS    50331648ull     // f32 [32][2048][4] {U, rbar, sbar, 0} 1048576
#define OFF_TPWB   51380736ull     // u16 [256][768]                        393216
#define OFF_WHHB   51773952ull     // u16 [384][128]  (exp2-prescaled)       98304
#define OFF_W1B    51872256ull     // u16 [192][384]                        147456
#define OFF_W2B    52019712ull     // u16 [16][192]                           6144
#define OFF_WABC   52025856ull     // f32 wA[256] wB[256] wC[256]             3072
#define OFF_CABC   52028928ull     // f32 cA cB cC pad                          16
#define OFF_GX     52028944ull     // f32 gxu[384] gxr[384] gxs[384] gxc[384] 6144
#define OFF_PROG   52035088ull     // i32 prog[32] GRU chunk progress          128
// gx rows j<256 (r,z): scaled by -log2e (includes folded b_hh).
// gx rows j>=256 (n): scaled by +2*log2e. whhb rows likewise prescaled.

// =====================================================================
// K0: derived weights + bf16 conversions (with exp2 prescale)
// =====================================================================
__global__ __launch_bounds__(512) void k_prep(
    const float* __restrict__ qw, const float* __restrict__ qb,
    const float* __restrict__ kw, const float* __restrict__ kb,
    const float* __restrict__ vw, const float* __restrict__ vb,
    const float* __restrict__ wih, const float* __restrict__ bih,
    const float* __restrict__ bhh,
    const float* __restrict__ tpw, const float* __restrict__ whh,
    const float* __restrict__ w1, const float* __restrict__ w2,
    u16* __restrict__ tpwb, u16* __restrict__ whhb,
    u16* __restrict__ w1b, u16* __restrict__ w2b,
    float* __restrict__ wabc, float* __restrict__ cabc, float* __restrict__ gx,
    int* __restrict__ prog) {
  const int tid = threadIdx.x, bid = blockIdx.x;
  if (bid == 0 && tid < 256) {
    int p = tid;
    float a = 0.f, b = 0.f, c = 0.f;
    for (int j = 0; j < 64; j++) {
      float q = qw[j * 256 + p];
      a += q * kw[2 * j]; b += q * kw[2 * j + 1]; c += q * kb[j];
    }
    wabc[p] = a; wabc[256 + p] = b; wabc[512 + p] = c;
    if (p == 0) {
      float ca = 0.f, cb = 0.f, cc = 0.f;
      for (int j = 0; j < 64; j++) {
        ca += qb[j] * kw[2 * j]; cb += qb[j] * kw[2 * j + 1]; cc += qb[j] * kb[j];
      }
      cabc[0] = ca; cabc[1] = cb; cabc[2] = cc; cabc[3] = 0.f;
    }
  }
  if (bid == 1 && tid < 384) {
    int j = tid;
    float r = 0.f, s = 0.f, c0 = 0.f;
    for (int v = 0; v < 64; v++) {
      float w = wih[j * 65 + 1 + v];
      r += w * vw[2 * v]; s += w * vw[2 * v + 1]; c0 += w * vb[v];
    }
    float xc = c0 + bih[j] + (j < 256 ? bhh[j] : 0.f);
    float sc = (j < 256) ? -L2E : L2E2;
    gx[j] = wih[j * 65] * sc; gx[384 + j] = r * sc;
    gx[768 + j] = s * sc;     gx[1152 + j] = xc * sc;
  }
  if (bid == 2 && tid < 32) prog[tid] = 0;   // reset GRU progress counters
  const int n1 = 768 * 256, n2 = 384 * 128, n3 = 192 * 384, n4 = 16 * 192;
  const int total = n1 + n2 + n3 + n4;
  for (int i = bid * blockDim.x + tid; i < total; i += gridDim.x * blockDim.x) {
    if (i < n1) tpwb[i] = f2b(tpw[i]);
    else if (i < n1 + n2) {
      int loc = i - n1;
      float sc = (loc < 256 * 128) ? L2E : L2E2;
      whhb[loc] = f2b(whh[loc] * sc);
    }
    else if (i < n1 + n2 + n3) w1b[i - n1 - n2] = f2b(w1[i - n1 - n2]);
    else w2b[i - n1 - n2 - n3] = f2b(w2[i - n1 - n2 - n3]);
  }
}

// =====================================================================
// K1: processed = relu(TE @ tp_w.T + tp_b) -> comb[:, 0:256] (bf16)
//     + fused collapsed attention -> urs.
// =====================================================================
#define PSTR 264
__global__ __launch_bounds__(512, 4) void k_gemm1(
    const float* __restrict__ te, const float* __restrict__ tpb,
    const u16* __restrict__ tpwb, u16* __restrict__ comb,
    const float* __restrict__ U, const float* __restrict__ R,
    const float* __restrict__ S, const float* __restrict__ wabc,
    const float* __restrict__ cabc, float* __restrict__ urs) {
  __shared__ u16 smem[128 * PSTR];  // 67584 B
  u16* Als = smem;                  // 128x64
  u16* Bls = smem + 8192;           // 256x64
  u16* ptile = smem;                // 128xPSTR (reuse after MFMA loop)
  const int tid = threadIdx.x;
  const int lane = tid & 63, w = tid >> 6;
  const int c = lane & 15, g4 = lane >> 4;
  const int wm = w >> 2, wn = w & 3;
  const long row0 = (long)blockIdx.x * 128;

  f32x4 acc[4][4];
  #pragma unroll
  for (int i = 0; i < 4; i++)
    #pragma unroll
    for (int j = 0; j < 4; j++) acc[i][j] = (f32x4)(0.f);

  for (int kk = 0; kk < 12; kk++) {
    #pragma unroll
    for (int ii = 0; ii < 2; ii++) {
      int idx = tid + 512 * ii;
      int row = idx >> 3, kb = idx & 7;
      const float* g = te + (row0 + row) * 768 + kk * 64 + kb * 8;
      f32x4 p0 = *(const f32x4*)g;
      f32x4 p1 = *(const f32x4*)(g + 4);
      u32x4 v;
      v[0] = pk2(p0[0], p0[1]); v[1] = pk2(p0[2], p0[3]);
      v[2] = pk2(p1[0], p1[1]); v[3] = pk2(p1[2], p1[3]);
      *(u32x4*)&Als[row * 64 + ((kb ^ (row & 7)) << 3)] = v;
    }
    #pragma unroll
    for (int ii = 0; ii < 4; ii++) {
      int idx = tid + 512 * ii;
      int n = idx >> 3, kb = idx & 7;
      s16x8 v = *(const s16x8*)(tpwb + n * 768 + kk * 64 + kb * 8);
      *(s16x8*)&Bls[n * 64 + ((kb ^ (n & 7)) << 3)] = v;
    }
    __syncthreads();
    #pragma unroll
    for (int kt = 0; kt < 2; kt++) {
      s16x8 af[4], bf[4];
      #pragma unroll
      for (int mt = 0; mt < 4; mt++) {
        int row = wm * 64 + mt * 16 + c;
        af[mt] = *(const s16x8*)&Als[row * 64 + (((kt * 4 + g4) ^ (row & 7)) << 3)];
      }
      #pragma unroll
      for (int nt = 0; nt < 4; nt++) {
        int n = wn * 64 + nt * 16 + c;
        bf[nt] = *(const s16x8*)&Bls[n * 64 + (((kt * 4 + g4) ^ (n & 7)) << 3)];
      }
      #pragma unroll
      for (int mt = 0; mt < 4; mt++)
        #pragma unroll
        for (int nt = 0; nt < 4; nt++)
          acc[mt][nt] = mfma16(af[mt], bf[nt], acc[mt][nt]);
    }
    __syncthreads();
  }
  // epilogue: relu + bias -> comb (global) and ptile (LDS, stride PSTR)
  #pragma unroll
  for (int nt = 0; nt < 4; nt++) {
    int col = wn * 64 + nt * 16 + c;
    float bias = tpb[col];
    #pragma unroll
    for (int mt = 0; mt < 4; mt++)
      #pragma unroll
      for (int r = 0; r < 4; r++) {
        int lr = wm * 64 + mt * 16 + g4 * 4 + r;
        float v = fmaxf(acc[mt][nt][r] + bias, 0.f);
        u16 hv = f2b(v);
        comb[(row0 + lr) * 384 + col] = hv;
        ptile[lr * PSTR + col] = hv;
      }
  }
  __syncthreads();

  // fused attention: wave w handles tokens row0 + w*16 .. +15
  {
    const int tok16 = lane >> 2;       // 0..15
    const int part = lane & 3;         // 0..3 (64-col slice)
    const int lr = w * 16 + tok16;
    const long tokg = row0 + lr;
    const int t = (int)(tokg & 2047);
    const int seq = (int)(tokg >> 11);
    const int m = seq & 3;

    float a = 0.f, b = 0.f, cd = 0.f;
    const u16* prow = &ptile[lr * PSTR + part * 64];
    #pragma unroll
    for (int i = 0; i < 8; i++) {
      s16x8 pv = *(const s16x8*)(prow + i * 8);
      int col0 = part * 64 + i * 8;
      f32x4 wa0 = *(const f32x4*)(wabc + col0);
      f32x4 wa1 = *(const f32x4*)(wabc + col0 + 4);
      f32x4 wb0 = *(const f32x4*)(wabc + 256 + col0);
      f32x4 wb1 = *(const f32x4*)(wabc + 256 + col0 + 4);
      f32x4 wc0 = *(const f32x4*)(wabc + 512 + col0);
      f32x4 wc1 = *(const f32x4*)(wabc + 512 + col0 + 4);
      #pragma unroll
      for (int k = 0; k < 4; k++) {
        float p = b2f((u16)pv[k]);
        a += p * wa0[k]; b += p * wb0[k]; cd += p * wc0[k];
      }
      #pragma unroll
      for (int k = 0; k < 4; k++) {
        float p = b2f((u16)pv[4 + k]);
        a += p * wa1[k]; b += p * wb1[k]; cd += p * wc1[k];
      }
    }
    #pragma unroll
    for (int off = 1; off <= 2; off <<= 1) {
      a += __shfl_xor(a, off); b += __shfl_xor(b, off); cd += __shfl_xor(cd, off);
    }
    a += cabc[0]; b += cabc[1]; cd += cabc[2];

    float rv[3], sv[3], sc[3];
    #pragma unroll
    for (int n = 0; n < 3; n++) {
      int o = n + (n >= m ? 1 : 0);
      long idx = ((long)seq * 4 + o) * 2048 + t;
      rv[n] = R[idx]; sv[n] = S[idx];
      sc[n] = (a * rv[n] + b * sv[n] + cd) * 0.125f;
    }
    float mx = fmaxf(sc[0], fmaxf(sc[1], sc[2]));
    float e0 = __expf(sc[0] - mx), e1 = __expf(sc[1] - mx), e2 = __expf(sc[2] - mx);
    float inv = rcp_fast(e0 + e1 + e2);
    float rb = (e0 * rv[0] + e1 * rv[1] + e2 * rv[2]) * inv;
    float sb = (e0 * sv[0] + e1 * sv[1] + e2 * sv[2]) * inv;
    if (part == 0) {
      f32x4 v; v[0] = U[tokg]; v[1] = rb; v[2] = sb; v[3] = 0.f;
      *(f32x4*)(urs + ((long)seq * 2048 + t) * 4) = v;
    }
  }
}

// =====================================================================
// K2: merged GRU + MLP. 256 blocks x 512 threads (<= 256 CUs: all blocks
// co-resident at launch => progress-wait cannot deadlock).
//  blocks 0-31 : R8's GRU (hot loop byte-identical) + agent-scope release
//                publish of prog[seq]=chunk+1 every 4 chunks (after the
//                flush-draining __syncthreads).
//  blocks 32+  : MLP workers. Tiles (tgroup 0..15, seq 0..31) of 128 rows;
//                tid0 spins (relaxed + s_sleep) until prog[seq] >= 4*(tg+1),
//                barrier, per-thread acquire load (cross-XCD L2 inv), then
//                the proven k_mlp body.
// =====================================================================
__global__ __launch_bounds__(512, 1) void k_gru_mlp(
    const u16* __restrict__ whhb, const float* __restrict__ bhh,
    const float* __restrict__ gx, const float* __restrict__ urs,
    u16* __restrict__ comb, const u16* __restrict__ w1b,
    const float* __restrict__ b1, const u16* __restrict__ w2b,
    const float* __restrict__ b2, float* __restrict__ out,
    int* __restrict__ prog) {
  __shared__ __align__(16) union {
    struct {
      u16 hbuf[2][128];          //   512 B
      u16 hist[2][32][128];      // 16384 B
      float ulds[2049][4];       // 32784 B
    } g;
    u16 m[24840];                // 49680 B (mlp uses first 49152)
  } SM;
  const int tid = threadIdx.x;
  const int bid = blockIdx.x;
  const int lane = tid & 63, w = tid >> 6;
  const int c = lane & 15, g4 = lane >> 4;

  if (bid < 32) {
    // ----------------- GRU path (R8 form) -----------------
    auto& hbuf = SM.g.hbuf;
    auto& hist = SM.g.hist;
    auto& ulds = SM.g.ulds;
    const int seq = bid;

    for (int i = tid; i < 2048; i += 512)
      *(f32x4*)&ulds[i][0] = *(const f32x4*)(urs + ((long)seq * 2048 + i) * 4);

    const int j = w * 16 + c;                  // this lane's H column (0..127)
    s16x8 bfr[3][4];
    #pragma unroll
    for (int g = 0; g < 3; g++) {
      int n = g * 128 + j;
      #pragma unroll
      for (int kt = 0; kt < 4; kt++)
        bfr[g][kt] = *(const s16x8*)(whhb + n * 128 + kt * 32 + g4 * 8);
    }
    float gxv[3][4];
    #pragma unroll
    for (int g = 0; g < 3; g++) {
      int jj = g * 128 + j;
      gxv[g][0] = gx[jj];        gxv[g][1] = gx[384 + jj];
      gxv[g][2] = gx[768 + jj];  gxv[g][3] = gx[1152 + jj];
    }
    const float bhn = bhh[256 + j] * L2E2;
    const f32x4 nseed = (f32x4)(bhn);

    if (tid < 128) { hbuf[0][tid] = 0; hbuf[1][tid] = 0; }
    float hprev = 0.f;
    __syncthreads();  // urs preload + hbuf visible

    float xq0, xq1, xq2;
    {
      f32x4 u0 = *(const f32x4*)&ulds[0][0];
      xq0 = gxv[0][3] + u0[0] * gxv[0][0] + u0[1] * gxv[0][1] + u0[2] * gxv[0][2];
      xq1 = gxv[1][3] + u0[0] * gxv[1][0] + u0[1] * gxv[1][1] + u0[2] * gxv[1][2];
      xq2 = gxv[2][3] + u0[0] * gxv[2][0] + u0[1] * gxv[2][1] + u0[2] * gxv[2][2];
    }

    u16* rbase = comb + (long)seq * 2048 * 384 + 256;
    for (int chunk = 0; chunk < 64; chunk++) {
      const float* up = &ulds[chunk * 32][0];
      u16* hw = &hist[chunk & 1][0][j];
      #pragma unroll 8
      for (int s = 0; s < 32; s++) {
        s16x8 af[4];
        #pragma unroll
        for (int kt = 0; kt < 4; kt++)
          af[kt] = *(const s16x8*)&hbuf[s & 1][kt * 32 + g4 * 8];
        f32x4 aA[3], aB[3];
        #pragma unroll
        for (int g = 0; g < 3; g++) {
          f32x4 x0 = (f32x4)(0.f);
          f32x4 x1 = (g == 2) ? nseed : (f32x4)(0.f);
          x0 = mfma16(af[0], bfr[g][0], x0);
          x1 = mfma16(af[2], bfr[g][2], x1);
          x0 = mfma16(af[1], bfr[g][1], x0);
          x1 = mfma16(af[3], bfr[g][3], x1);
          aA[g] = x0; aB[g] = x1;
        }
        f32x4 un = *(const f32x4*)(up + (s + 1) * 4);
        float nx0 = gxv[0][3] + un[0] * gxv[0][0] + un[1] * gxv[0][1] + un[2] * gxv[0][2];
        float nx1 = gxv[1][3] + un[0] * gxv[1][0] + un[1] * gxv[1][1] + un[2] * gxv[1][2];
        float nx2 = gxv[2][3] + un[0] * gxv[2][0] + un[1] * gxv[2][1] + un[2] * gxv[2][2];
        float hr2 = aA[0][0] + aB[0][0];
        float hz2 = aA[1][0] + aB[1][0];
        float hn2 = aA[2][0] + aB[2][0];
        float r = rcp_fast(1.f + exp2_fast(xq0 - hr2));
        float z = rcp_fast(1.f + exp2_fast(xq1 - hz2));
        float e = exp2_fast(xq2 + r * hn2);
        float n = __builtin_fmaf(-2.f, rcp_fast(e + 1.f), 1.f);
        float h = z * (hprev - n) + n;
        hprev = h;
        u16 hb = f2b_cvt(h);
        hbuf[(s + 1) & 1][j] = hb;
        hw[s * 128] = hb;
        __syncthreads();
        xq0 = nx0; xq1 = nx1; xq2 = nx2;
      }
      // flush chunk history: 32 rows x 256 B, coalesced 16 B fire-and-forget
      const int t0 = chunk * 32;
      {
        int row = tid >> 4, part = tid & 15;
        s16x8 v = *(const s16x8*)&hist[chunk & 1][row][part * 8];
        *(s16x8*)(rbase + (long)(t0 + row) * 384 + part * 8) = v;
      }
      // publish progress every 4 chunks: barrier drains all threads' flush
      // stores (vmcnt), release-store writes back L2 for cross-XCD readers
      if ((chunk & 3) == 3) {
        __syncthreads();
        if (tid == 0)
          __hip_atomic_store(&prog[seq], chunk + 1,
                             __ATOMIC_RELEASE, __HIP_MEMORY_SCOPE_AGENT);
      }
    }
  } else {
    // ----------------- MLP worker path -----------------
    u16* Als = SM.m;             // 128x64
    u16* Bls = SM.m + 8192;      // 192x64
    u16* Hls = SM.m;             // 128x192 (reuse after barrier)
    const int wm = w >> 2, wn = w & 3;

    s16x8 w2f[6];
    #pragma unroll
    for (int kt = 0; kt < 6; kt++)
      w2f[kt] = *(const s16x8*)(w2b + c * 192 + kt * 32 + g4 * 8);
    const float b2v = b2[c];

    for (int q = bid - 32; q < 512; q += 224) {
      const int tg = q >> 5, seq = q & 31;
      const long row0 = (long)seq * 2048 + (long)tg * 128;
      const int need = (tg + 1) * 4;
      if (tid == 0) {
        while (__hip_atomic_load(&prog[seq], __ATOMIC_RELAXED,
                                 __HIP_MEMORY_SCOPE_AGENT) < need)
          __builtin_amdgcn_s_sleep(8);
      }
      __syncthreads();   // all threads see readiness; orders prior tile's LDS reuse
      (void)__hip_atomic_load(&prog[seq], __ATOMIC_ACQUIRE,
                              __HIP_MEMORY_SCOPE_AGENT);  // L1/L2 inv for comb reads

      f32x4 acc[4][3];
      #pragma unroll
      for (int i = 0; i < 4; i++)
        #pragma unroll
        for (int jj = 0; jj < 3; jj++) acc[i][jj] = (f32x4)(0.f);

      for (int kc = 0; kc < 6; kc++) {
        #pragma unroll
        for (int ii = 0; ii < 2; ii++) {
          int idx = tid + 512 * ii;
          int row = idx >> 3, kb = idx & 7;
          s16x8 v = *(const s16x8*)(comb + (row0 + row) * 384 + kc * 64 + kb * 8);
          *(s16x8*)&Als[row * 64 + ((kb ^ (row & 7)) << 3)] = v;
        }
        #pragma unroll
        for (int ii = 0; ii < 3; ii++) {
          int idx = tid + 512 * ii;
          if (idx < 1536) {
            int n = idx >> 3, kb = idx & 7;
            s16x8 v = *(const s16x8*)(w1b + n * 384 + kc * 64 + kb * 8);
            *(s16x8*)&Bls[n * 64 + ((kb ^ (n & 7)) << 3)] = v;
          }
        }
        __syncthreads();
        #pragma unroll
        for (int kt = 0; kt < 2; kt++) {
          s16x8 af[4], bf[3];
          #pragma unroll
          for (int mt = 0; mt < 4; mt++) {
            int row = wm * 64 + mt * 16 + c;
            af[mt] = *(const s16x8*)&Als[row * 64 + (((kt * 4 + g4) ^ (row & 7)) << 3)];
          }
          #pragma unroll
          for (int nt = 0; nt < 3; nt++) {
            int n = wn * 48 + nt * 16 + c;
            bf[nt] = *(const s16x8*)&Bls[n * 64 + (((kt * 4 + g4) ^ (n & 7)) << 3)];
          }
          #pragma unroll
          for (int mt = 0; mt < 4; mt++)
            #pragma unroll
            for (int nt = 0; nt < 3; nt++)
              acc[mt][nt] = mfma16(af[mt], bf[nt], acc[mt][nt]);
        }
        __syncthreads();
      }
      // hid -> LDS (bf16, swizzled)
      #pragma unroll
      for (int nt = 0; nt < 3; nt++) {
        int col = wn * 48 + nt * 16 + c;
        float bias = b1[col];
        int cb = col >> 3, cl = col & 7;
        #pragma unroll
        for (int mt = 0; mt < 4; mt++)
          #pragma unroll
          for (int r = 0; r < 4; r++) {
            int row = wm * 64 + mt * 16 + g4 * 4 + r;
            float v = fmaxf(acc[mt][nt][r] + bias, 0.f);
            Hls[row * 192 + ((cb ^ (row & 7)) << 3) + cl] = f2b(v);
          }
      }
      __syncthreads();
      // gemm2: 16 outputs, K=192
      f32x4 a2 = (f32x4)(0.f);
      const int row = w * 16 + c, r7 = row & 7;
      #pragma unroll
      for (int kt = 0; kt < 6; kt++) {
        s16x8 af = *(const s16x8*)&Hls[row * 192 + (((kt * 4 + g4) ^ r7) << 3)];
        a2 = mfma16(af, w2f[kt], a2);
      }
      #pragma unroll
      for (int r = 0; r < 4; r++) {
        long grow = row0 + w * 16 + g4 * 4 + r;
        out[grow * 16 + c] = a2[r] + b2v;
      }
      __syncthreads();   // Hls reads done before next tile's Als staging
    }
  }
}

// =====================================================================
extern "C" void kernel_launch(void* const* d_in, const int* in_sizes, int n_in,
                              void* d_out, int out_size, void* d_ws, size_t ws_size,
                              hipStream_t stream) {
  (void)in_sizes; (void)n_in; (void)out_size; (void)ws_size;
  const float* te  = (const float*)d_in[0];
  const float* U   = (const float*)d_in[1];
  const float* R   = (const float*)d_in[2];
  const float* S   = (const float*)d_in[3];
  const float* tpw = (const float*)d_in[4];
  const float* tpb = (const float*)d_in[5];
  const float* qw  = (const float*)d_in[6];
  const float* qb  = (const float*)d_in[7];
  const float* kw  = (const float*)d_in[8];
  const float* kb  = (const float*)d_in[9];
  const float* vw  = (const float*)d_in[10];
  const float* vb  = (const float*)d_in[11];
  const float* wih = (const float*)d_in[12];
  const float* whh = (const float*)d_in[13];
  const float* bih = (const float*)d_in[14];
  const float* bhh = (const float*)d_in[15];
  const float* w1  = (const float*)d_in[16];
  const float* b1  = (const float*)d_in[17];
  const float* w2  = (const float*)d_in[18];
  const float* b2  = (const float*)d_in[19];

  char* ws = (char*)d_ws;
  u16*   comb = (u16*)(ws + OFF_COMB);
  float* urs  = (float*)(ws + OFF_URS);
  u16*   tpwb = (u16*)(ws + OFF_TPWB);
  u16*   whhb = (u16*)(ws + OFF_WHHB);
  u16*   w1b  = (u16*)(ws + OFF_W1B);
  u16*   w2b  = (u16*)(ws + OFF_W2B);
  float* wabc = (float*)(ws + OFF_WABC);
  float* cabc = (float*)(ws + OFF_CABC);
  float* gx   = (float*)(ws + OFF_GX);
  int*   prog = (int*)(ws + OFF_PROG);
  float* out  = (float*)d_out;

  hipLaunchKernelGGL(k_prep, dim3(32), dim3(512), 0, stream,
                     qw, qb, kw, kb, vw, vb, wih, bih, bhh, tpw, whh, w1, w2,
                     tpwb, whhb, w1b, w2b, wabc, cabc, gx, prog);
  hipLaunchKernelGGL(k_gemm1, dim3(512), dim3(512), 0, stream,
                     te, tpb, tpwb, comb, U, R, S, wabc, cabc, urs);
  hipLaunchKernelGGL(k_gru_mlp, dim3(256), dim3(512), 0, stream,
                     whhb, bhh, gx, urs, comb, w1b, b1, w2b, b2, out, prog);
}